// Round 3
// baseline (2064.926 us; speedup 1.0000x reference)
//
#include <hip/hip_runtime.h>

#define EDGES 1000000
#define NODES 100000
#define ET 128   // edges per tile
#define NB 64    // nodes per block (node_kernel)
#define NBLK ((NODES + NB - 1) / NB)  // 1563

typedef short short8 __attribute__((ext_vector_type(8)));
typedef float floatx4 __attribute__((ext_vector_type(4)));

#define MFMA(a, b, c) __builtin_amdgcn_mfma_f32_16x16x32_bf16(a, b, c, 0, 0, 0)

// ws layout (bytes)
#define WS_WX1 0        // 32768: Wx1 bf16 frags
#define WS_WX2 32768    // 16384: Wx2 frags
#define WS_WP1 49152    // 16384: Wp1 frags
#define WS_MISC 65536   // 2048: biases etc (floats)
#define WS_OFF 68608    // off[100128] int = 400512 B (CSR offsets, padded)
#define WS_CNT 469504   // counts/cursor[100000] int = 400000 B (aliased)
#define WS_SREC 917504  // uint2[EDGES] = 8 MB sorted (row,col) records
// total ws need: ~9.31 MB

__device__ __forceinline__ unsigned short f2bf(float f) {
  union { float f; unsigned int u; } c;
  c.f = f;
  unsigned int u = c.u;
  u += 0x7fffu + ((u >> 16) & 1u);
  return (unsigned short)(u >> 16);
}

__device__ __forceinline__ float fast_silu(float v) {
#if __has_builtin(__builtin_amdgcn_exp2f) && __has_builtin(__builtin_amdgcn_rcpf)
  float e = __builtin_amdgcn_exp2f(-1.44269504088896340736f * v);
  return v * __builtin_amdgcn_rcpf(1.0f + e);
#else
  return v / (1.0f + __expf(-v));
#endif
}

__global__ __launch_bounds__(256) void prep_kernel(
    const float* __restrict__ Wx1, const float* __restrict__ Wx2,
    const float* __restrict__ Wp1, const float* __restrict__ bx1,
    const float* __restrict__ bx2, const float* __restrict__ bp1,
    const float* __restrict__ Wp2, const float* __restrict__ bp2,
    unsigned char* __restrict__ ws) {
  const int t = blockIdx.x * 256 + threadIdx.x;
  const int nthr = gridDim.x * 256;

  for (int task = t; task < 2048; task += nthr) {  // Wx1[0:128][0:128]
    const int n = task & 127;
    const int kb = task >> 7;
    const int k0 = kb << 3;
    unsigned int d[4];
#pragma unroll
    for (int i = 0; i < 4; ++i) {
      unsigned short lo = f2bf(Wx1[(k0 + 2 * i) * 128 + n]);
      unsigned short hi = f2bf(Wx1[(k0 + 2 * i + 1) * 128 + n]);
      d[i] = (unsigned int)lo | ((unsigned int)hi << 16);
    }
    const int lane = ((kb & 3) << 4) | (n & 15);
    const int frag = ((kb >> 2) << 3) | (n >> 4);
    *(uint4*)(ws + WS_WX1 + ((size_t)(frag * 64 + lane) << 4)) =
        make_uint4(d[0], d[1], d[2], d[3]);
  }
  for (int task = t; task < 1024; task += nthr) {  // Wx2[0:128][0:64]
    const int n = task & 63;
    const int kb = task >> 6;
    const int k0 = kb << 3;
    unsigned int d[4];
#pragma unroll
    for (int i = 0; i < 4; ++i) {
      unsigned short lo = f2bf(Wx2[(k0 + 2 * i) * 64 + n]);
      unsigned short hi = f2bf(Wx2[(k0 + 2 * i + 1) * 64 + n]);
      d[i] = (unsigned int)lo | ((unsigned int)hi << 16);
    }
    const int lane = ((kb & 3) << 4) | (n & 15);
    const int frag = ((kb >> 2) << 2) | (n >> 4);
    *(uint4*)(ws + WS_WX2 + ((size_t)(frag * 64 + lane) << 4)) =
        make_uint4(d[0], d[1], d[2], d[3]);
  }
  for (int task = t; task < 1024; task += nthr) {  // Wp1[0:64][0:128]
    const int n = task & 127;
    const int kb = task >> 7;
    const int k0 = kb << 3;
    unsigned int d[4];
#pragma unroll
    for (int i = 0; i < 4; ++i) {
      unsigned short lo = f2bf(Wp1[(k0 + 2 * i) * 128 + n]);
      unsigned short hi = f2bf(Wp1[(k0 + 2 * i + 1) * 128 + n]);
      d[i] = (unsigned int)lo | ((unsigned int)hi << 16);
    }
    const int lane = ((kb & 3) << 4) | (n & 15);
    const int frag = ((kb >> 2) << 3) | (n >> 4);
    *(uint4*)(ws + WS_WP1 + ((size_t)(frag * 64 + lane) << 4)) =
        make_uint4(d[0], d[1], d[2], d[3]);
  }
  float* misc = (float*)(ws + WS_MISC);
  for (int i = t; i < 128; i += nthr) misc[i] = bx1[i];
  for (int i = t; i < 64; i += nthr) misc[128 + i] = bx2[i];
  for (int i = t; i < 128; i += nthr) misc[192 + i] = bp1[i];
  for (int i = t; i < 128; i += nthr) misc[320 + i] = Wp2[i];
  if (t == 0) misc[448] = bp2[0];
  for (int i = t; i < 128; i += nthr) misc[456 + i] = Wx1[128 * 128 + i];
}

// ---- counting sort by col ----
__global__ __launch_bounds__(256) void hist_kernel(const int* __restrict__ ei,
                                                   int* __restrict__ counts) {
  const int t = blockIdx.x * 256 + threadIdx.x;
  if (t < EDGES) {
    int c = ei[EDGES + t];
    c = (c < 0) ? 0 : ((c >= NODES) ? NODES - 1 : c);
    atomicAdd(&counts[c], 1);
  }
}

#define SCAN_T 1024
#define SCAN_C 98  // 1024*98 = 100352 >= NODES

__global__ __launch_bounds__(SCAN_T) void scan_kernel(int* __restrict__ counts,
                                                      int* __restrict__ off,
                                                      int* __restrict__ cursor) {
  __shared__ int part[SCAN_T];
  const int t = threadIdx.x;
  const int lo = t * SCAN_C;
  const int hi = (lo + SCAN_C < NODES) ? lo + SCAN_C : NODES;
  int s = 0;
  for (int i = lo; i < hi; ++i) s += counts[i];
  part[t] = s;
  __syncthreads();
  for (int d = 1; d < SCAN_T; d <<= 1) {  // Hillis-Steele inclusive scan
    int v = 0;
    if (t >= d) v = part[t - d];
    __syncthreads();
    if (t >= d) part[t] += v;
    __syncthreads();
  }
  int run = (t == 0) ? 0 : part[t - 1];
  for (int i = lo; i < hi; ++i) {
    const int cn = counts[i];  // read BEFORE cursor write (aliased buffers)
    off[i] = run;
    cursor[i] = run;
    run += cn;
  }
  for (int i = NODES + t; i < NODES + 128; i += SCAN_T) off[i] = EDGES;
}

__global__ __launch_bounds__(256) void scatter_kernel(const int* __restrict__ ei,
                                                      int* __restrict__ cursor,
                                                      uint2* __restrict__ srec) {
  const int t = blockIdx.x * 256 + threadIdx.x;
  if (t < EDGES) {
    int r = ei[t];
    int c = ei[EDGES + t];
    r = (r < 0) ? 0 : ((r >= NODES) ? NODES - 1 : r);
    c = (c < 0) ? 0 : ((c >= NODES) ? NODES - 1 : c);
    const int p = atomicAdd(&cursor[c], 1);
    srec[p] = make_uint2((unsigned)r, (unsigned)c);
  }
}

// ---- main: node-centric, zero global atomics ----
__global__ __launch_bounds__(256, 3) void node_kernel(
    const float* __restrict__ x, const float* __restrict__ pos,
    const unsigned char* __restrict__ ws, float* __restrict__ out) {
  __shared__ uint4 sFeat[2048];                    // 32 KB B-operand frags
  __shared__ __align__(16) float sAccX[NB * 68];   // stride 68: ds-atomic banks ~2-way
  __shared__ float sAccP[NB * 4];
  __shared__ float sRel[ET * 3];
  __shared__ float sDist[ET];
  __shared__ int sLC[ET];
  __shared__ int sRowE[ET];

  const int tid = threadIdx.x;
  const int lane = tid & 63;
  const int wave = tid >> 6;
  const int q = lane >> 4;
  const int nn = lane & 15;
  const int base = blockIdx.x * NB;

  const int* off = (const int*)(ws + WS_OFF);
  const uint2* srec = (const uint2*)(ws + WS_SREC);
  const uint4* wx1f = (const uint4*)(ws + WS_WX1);
  const uint4* wx2f = (const uint4*)(ws + WS_WX2);
  const uint4* wp1f = (const uint4*)(ws + WS_WP1);
  const float* misc = (const float*)(ws + WS_MISC);

  const int e0 = off[base];
  const int e1 = off[base + NB];

  for (int i = tid; i < NB * 68; i += 256) sAccX[i] = 0.f;
  if (tid < NB * 4) sAccP[tid] = 0.f;
  __syncthreads();

  const int et0 = wave * 2;
  const floatx4 fzero = {0.f, 0.f, 0.f, 0.f};

  for (int t0 = e0; t0 < e1; t0 += ET) {
    // ---- phase A: edge records, rel_pos, dist
    if (tid < ET) {
      const int e = t0 + tid;
      int r = 0, lc = 0;
      float r0 = 0.f, r1 = 0.f, r2 = 0.f, dd = 0.f;
      if (e < e1) {
        const uint2 rc = srec[e];
        r = (int)rc.x;
        const int c = (int)rc.y;
        lc = c - base;
        lc = (lc < 0) ? 0 : ((lc > NB - 1) ? NB - 1 : lc);
        r0 = pos[3 * r + 0] - pos[3 * c + 0];
        r1 = pos[3 * r + 1] - pos[3 * c + 1];
        r2 = pos[3 * r + 2] - pos[3 * c + 2];
        dd = r0 * r0 + r1 * r1 + r2 * r2;
      }
      sRowE[tid] = r;
      sLC[tid] = lc;
      sRel[3 * tid + 0] = r0;
      sRel[3 * tid + 1] = r1;
      sRel[3 * tid + 2] = r2;
      sDist[tid] = dd;
    }
    __syncthreads();

    // ---- phase B: x[row] (k 0..63) and x[col] (k 64..127; sorted → L1 hits)
    {
      const int e = tid & (ET - 1);
      const int p = tid >> 7;
      const bool valid = (t0 + e) < e1;
      const int node = p ? (base + sLC[e]) : sRowE[e];
      const float4* src = (const float4*)(x + (size_t)node * 64);
      const int et = e >> 4;
      const int ml = e & 15;
#pragma unroll
      for (int g = 0; g < 8; ++g) {
        float4 a = valid ? src[2 * g + 0] : make_float4(0.f, 0.f, 0.f, 0.f);
        float4 b = valid ? src[2 * g + 1] : make_float4(0.f, 0.f, 0.f, 0.f);
        unsigned int d0 = (unsigned int)f2bf(a.x) | ((unsigned int)f2bf(a.y) << 16);
        unsigned int d1 = (unsigned int)f2bf(a.z) | ((unsigned int)f2bf(a.w) << 16);
        unsigned int d2 = (unsigned int)f2bf(b.x) | ((unsigned int)f2bf(b.y) << 16);
        unsigned int d3 = (unsigned int)f2bf(b.z) | ((unsigned int)f2bf(b.w) << 16);
        const int kf = p * 64 + g * 8;
        const int kt = kf >> 5;
        const int fl = (((kf & 31) >> 3) << 4) | ml;
        sFeat[(et * 4 + kt) * 64 + fl] = make_uint4(d0, d1, d2, d3);
      }
    }
    __syncthreads();

    // ---- GEMM1' + phi_pos
    floatx4 acc1[2][8], accp[2][8];
#pragma unroll
    for (int m = 0; m < 2; ++m)
#pragma unroll
      for (int j = 0; j < 8; ++j) {
        acc1[m][j] = fzero;
        accp[m][j] = fzero;
      }
#pragma unroll
    for (int kt = 0; kt < 4; ++kt) {
      const short8 b0 = __builtin_bit_cast(short8, sFeat[((et0 + 0) * 4 + kt) * 64 + lane]);
      const short8 b1 = __builtin_bit_cast(short8, sFeat[((et0 + 1) * 4 + kt) * 64 + lane]);
#pragma unroll
      for (int jt = 0; jt < 8; ++jt) {
        const short8 a = __builtin_bit_cast(short8, wx1f[(kt * 8 + jt) * 64 + lane]);
        acc1[0][jt] = MFMA(a, b0, acc1[0][jt]);
        acc1[1][jt] = MFMA(a, b1, acc1[1][jt]);
      }
      if (kt < 2) {
#pragma unroll
        for (int jt = 0; jt < 8; ++jt) {
          const short8 a = __builtin_bit_cast(short8, wp1f[(kt * 8 + jt) * 64 + lane]);
          accp[0][jt] = MFMA(a, b0, accp[0][jt]);
          accp[1][jt] = MFMA(a, b1, accp[1][jt]);
        }
      }
    }

    // ---- phi_pos epilogue → LDS accumulate
    float wvv[2];
#pragma unroll
    for (int m = 0; m < 2; ++m) {
      float s = 0.f;
#pragma unroll
      for (int jt = 0; jt < 8; ++jt) {
        const float4 bp = *(const float4*)(misc + 192 + jt * 16 + q * 4);
        const float4 wp = *(const float4*)(misc + 320 + jt * 16 + q * 4);
        s += fast_silu(accp[m][jt][0] + bp.x) * wp.x;
        s += fast_silu(accp[m][jt][1] + bp.y) * wp.y;
        s += fast_silu(accp[m][jt][2] + bp.z) * wp.z;
        s += fast_silu(accp[m][jt][3] + bp.w) * wp.w;
      }
      s += __shfl_xor(s, 16);
      s += __shfl_xor(s, 32);
      wvv[m] = s + misc[448];
    }
    if (q == 0) {
#pragma unroll
      for (int m = 0; m < 2; ++m) {
        const int el = (et0 + m) * 16 + nn;
        if (t0 + el < e1) {
          const int lc = sLC[el];
          atomicAdd(&sAccP[lc * 4 + 0], wvv[m] * sRel[3 * el + 0]);
          atomicAdd(&sAccP[lc * 4 + 1], wvv[m] * sRel[3 * el + 1]);
          atomicAdd(&sAccP[lc * 4 + 2], wvv[m] * sRel[3 * el + 2]);
        }
      }
    }

    // ---- epilogue 1: h = silu(...) → bf16 B-frags (wave-private sFeat region)
#pragma unroll
    for (int m = 0; m < 2; ++m) {
      const int etG = et0 + m;
      const float dist = sDist[etG * 16 + nn];
#pragma unroll
      for (int jt = 0; jt < 8; ++jt) {
        const float4 bx = *(const float4*)(misc + 0 + jt * 16 + q * 4);
        const float4 wd = *(const float4*)(misc + 456 + jt * 16 + q * 4);
        const unsigned short h0 = f2bf(fast_silu(acc1[m][jt][0] + bx.x + dist * wd.x));
        const unsigned short h1 = f2bf(fast_silu(acc1[m][jt][1] + bx.y + dist * wd.y));
        const unsigned short h2 = f2bf(fast_silu(acc1[m][jt][2] + bx.z + dist * wd.z));
        const unsigned short h3 = f2bf(fast_silu(acc1[m][jt][3] + bx.w + dist * wd.w));
        const int j0 = jt * 16 + q * 4;
        const int kt2 = j0 >> 5;
        const int lane2 = (((j0 & 31) >> 3) << 4) | nn;
        const int byteoff = (j0 & 7) << 1;
        uint2* dst = (uint2*)((char*)sFeat +
                              (((size_t)((etG * 4 + kt2) * 64 + lane2)) << 4) + byteoff);
        *dst = make_uint2((unsigned int)h0 | ((unsigned int)h1 << 16),
                          (unsigned int)h2 | ((unsigned int)h3 << 16));
      }
    }

    // ---- GEMM2'
    floatx4 acc2[2][4];
#pragma unroll
    for (int m = 0; m < 2; ++m)
#pragma unroll
      for (int it = 0; it < 4; ++it) acc2[m][it] = fzero;
#pragma unroll
    for (int kt = 0; kt < 4; ++kt) {
      const short8 b0 = __builtin_bit_cast(short8, sFeat[((et0 + 0) * 4 + kt) * 64 + lane]);
      const short8 b1 = __builtin_bit_cast(short8, sFeat[((et0 + 1) * 4 + kt) * 64 + lane]);
#pragma unroll
      for (int it = 0; it < 4; ++it) {
        const short8 a = __builtin_bit_cast(short8, wx2f[(kt * 4 + it) * 64 + lane]);
        acc2[0][it] = MFMA(a, b0, acc2[0][it]);
        acc2[1][it] = MFMA(a, b1, acc2[1][it]);
      }
    }

    // ---- epilogue 2: +bx2 per edge, LDS accumulate per local node
#pragma unroll
    for (int m = 0; m < 2; ++m) {
      const int el = (et0 + m) * 16 + nn;
      const bool v = (t0 + el) < e1;
      const int lc = sLC[el];
      float* arow = sAccX + lc * 68;
#pragma unroll
      for (int it = 0; it < 4; ++it) {
        const float4 b2 = *(const float4*)(misc + 128 + it * 16 + q * 4);
        if (v) {
          const int i0 = it * 16 + q * 4;
          atomicAdd(arow + i0 + 0, acc2[m][it][0] + b2.x);
          atomicAdd(arow + i0 + 1, acc2[m][it][1] + b2.y);
          atomicAdd(arow + i0 + 2, acc2[m][it][2] + b2.z);
          atomicAdd(arow + i0 + 3, acc2[m][it][3] + b2.w);
        }
      }
    }
    __syncthreads();
  }

  // ---- final coalesced stores (no global atomics)
  {
    const int n = base + (tid >> 2);
    if (n < NODES) {
      const int c0 = (tid & 3) * 16;
      float* orow = out + (size_t)n * 64 + c0;
      const float* arow = sAccX + (tid >> 2) * 68 + c0;
#pragma unroll
      for (int j = 0; j < 16; j += 4) *(float4*)(orow + j) = *(const float4*)(arow + j);
    }
    if (tid < 192) {
      const int idx = base * 3 + tid;
      if (idx < NODES * 3)
        out[(size_t)NODES * 64 + idx] = sAccP[(tid / 3) * 4 + (tid % 3)];
    }
  }
}

extern "C" void kernel_launch(void* const* d_in, const int* in_sizes, int n_in,
                              void* d_out, int out_size, void* d_ws, size_t ws_size,
                              hipStream_t stream) {
  (void)in_sizes; (void)n_in; (void)ws_size; (void)out_size;
  const float* x = (const float*)d_in[0];
  const float* pos = (const float*)d_in[1];
  const int* ei = (const int*)d_in[2];
  const float* Wx1 = (const float*)d_in[3];
  const float* bx1 = (const float*)d_in[4];
  const float* Wx2 = (const float*)d_in[5];
  const float* bx2 = (const float*)d_in[6];
  const float* Wp1 = (const float*)d_in[7];
  const float* bp1 = (const float*)d_in[8];
  const float* Wp2 = (const float*)d_in[9];
  const float* bp2 = (const float*)d_in[10];
  float* out = (float*)d_out;
  unsigned char* ws = (unsigned char*)d_ws;

  int* counts = (int*)(ws + WS_CNT);   // aliased with cursor (scan rewrites)
  int* cursor = (int*)(ws + WS_CNT);
  int* off = (int*)(ws + WS_OFF);
  uint2* srec = (uint2*)(ws + WS_SREC);

  hipMemsetAsync(counts, 0, (size_t)NODES * sizeof(int), stream);
  prep_kernel<<<16, 256, 0, stream>>>(Wx1, Wx2, Wp1, bx1, bx2, bp1, Wp2, bp2, ws);
  const int eb = (EDGES + 255) / 256;
  hist_kernel<<<eb, 256, 0, stream>>>(ei, counts);
  scan_kernel<<<1, SCAN_T, 0, stream>>>(counts, off, cursor);
  scatter_kernel<<<eb, 256, 0, stream>>>(ei, cursor, srec);
  node_kernel<<<NBLK, 256, 0, stream>>>(x, pos, ws, out);
}

// Round 4
// 1497.381 us; speedup vs baseline: 1.3790x; 1.3790x over previous
//
#include <hip/hip_runtime.h>

#define EDGES 1000000
#define NODES 100000
#define ET 128   // edges per tile
#define NB 64    // nodes per block (node_kernel)
#define NBLK ((NODES + NB - 1) / NB)  // 1563

typedef short short8 __attribute__((ext_vector_type(8)));
typedef float floatx4 __attribute__((ext_vector_type(4)));

#define MFMA(a, b, c) __builtin_amdgcn_mfma_f32_16x16x32_bf16(a, b, c, 0, 0, 0)

// ws layout (bytes)
#define WS_WX1 0        // 32768: Wx1 bf16 frags
#define WS_WX2 32768    // 16384: Wx2 frags
#define WS_WP1 49152    // 16384: Wp1 frags
#define WS_MISC 65536   // 2048: biases etc (floats)
#define WS_OFF 68608    // off[100128] int = 400512 B (CSR offsets, padded)
#define WS_CNT 469504   // counts/cursor[100000] int = 400000 B (aliased)
#define WS_SREC 917504  // uint2[EDGES] = 8 MB sorted (row,col) records
// total ws need: ~9.31 MB

__device__ __forceinline__ unsigned short f2bf(float f) {
  union { float f; unsigned int u; } c;
  c.f = f;
  unsigned int u = c.u;
  u += 0x7fffu + ((u >> 16) & 1u);
  return (unsigned short)(u >> 16);
}

__device__ __forceinline__ float fast_silu(float v) {
#if __has_builtin(__builtin_amdgcn_exp2f) && __has_builtin(__builtin_amdgcn_rcpf)
  float e = __builtin_amdgcn_exp2f(-1.44269504088896340736f * v);
  return v * __builtin_amdgcn_rcpf(1.0f + e);
#else
  return v / (1.0f + __expf(-v));
#endif
}

__global__ __launch_bounds__(256) void prep_kernel(
    const float* __restrict__ Wx1, const float* __restrict__ Wx2,
    const float* __restrict__ Wp1, const float* __restrict__ bx1,
    const float* __restrict__ bx2, const float* __restrict__ bp1,
    const float* __restrict__ Wp2, const float* __restrict__ bp2,
    unsigned char* __restrict__ ws) {
  const int t = blockIdx.x * 256 + threadIdx.x;
  const int nthr = gridDim.x * 256;

  for (int task = t; task < 2048; task += nthr) {  // Wx1[0:128][0:128]
    const int n = task & 127;
    const int kb = task >> 7;
    const int k0 = kb << 3;
    unsigned int d[4];
#pragma unroll
    for (int i = 0; i < 4; ++i) {
      unsigned short lo = f2bf(Wx1[(k0 + 2 * i) * 128 + n]);
      unsigned short hi = f2bf(Wx1[(k0 + 2 * i + 1) * 128 + n]);
      d[i] = (unsigned int)lo | ((unsigned int)hi << 16);
    }
    const int lane = ((kb & 3) << 4) | (n & 15);
    const int frag = ((kb >> 2) << 3) | (n >> 4);
    *(uint4*)(ws + WS_WX1 + ((size_t)(frag * 64 + lane) << 4)) =
        make_uint4(d[0], d[1], d[2], d[3]);
  }
  for (int task = t; task < 1024; task += nthr) {  // Wx2[0:128][0:64]
    const int n = task & 63;
    const int kb = task >> 6;
    const int k0 = kb << 3;
    unsigned int d[4];
#pragma unroll
    for (int i = 0; i < 4; ++i) {
      unsigned short lo = f2bf(Wx2[(k0 + 2 * i) * 64 + n]);
      unsigned short hi = f2bf(Wx2[(k0 + 2 * i + 1) * 64 + n]);
      d[i] = (unsigned int)lo | ((unsigned int)hi << 16);
    }
    const int lane = ((kb & 3) << 4) | (n & 15);
    const int frag = ((kb >> 2) << 2) | (n >> 4);
    *(uint4*)(ws + WS_WX2 + ((size_t)(frag * 64 + lane) << 4)) =
        make_uint4(d[0], d[1], d[2], d[3]);
  }
  for (int task = t; task < 1024; task += nthr) {  // Wp1[0:64][0:128]
    const int n = task & 127;
    const int kb = task >> 7;
    const int k0 = kb << 3;
    unsigned int d[4];
#pragma unroll
    for (int i = 0; i < 4; ++i) {
      unsigned short lo = f2bf(Wp1[(k0 + 2 * i) * 128 + n]);
      unsigned short hi = f2bf(Wp1[(k0 + 2 * i + 1) * 128 + n]);
      d[i] = (unsigned int)lo | ((unsigned int)hi << 16);
    }
    const int lane = ((kb & 3) << 4) | (n & 15);
    const int frag = ((kb >> 2) << 3) | (n >> 4);
    *(uint4*)(ws + WS_WP1 + ((size_t)(frag * 64 + lane) << 4)) =
        make_uint4(d[0], d[1], d[2], d[3]);
  }
  float* misc = (float*)(ws + WS_MISC);
  for (int i = t; i < 128; i += nthr) misc[i] = bx1[i];
  for (int i = t; i < 64; i += nthr) misc[128 + i] = bx2[i];
  for (int i = t; i < 128; i += nthr) misc[192 + i] = bp1[i];
  for (int i = t; i < 128; i += nthr) misc[320 + i] = Wp2[i];
  if (t == 0) misc[448] = bp2[0];
  for (int i = t; i < 128; i += nthr) misc[456 + i] = Wx1[128 * 128 + i];
}

// ---- counting sort by col ----
__global__ __launch_bounds__(256) void hist_kernel(const int* __restrict__ ei,
                                                   int* __restrict__ counts) {
  const int t = blockIdx.x * 256 + threadIdx.x;
  if (t < EDGES) {
    int c = ei[EDGES + t];
    c = (c < 0) ? 0 : ((c >= NODES) ? NODES - 1 : c);
    atomicAdd(&counts[c], 1);
  }
}

#define SCAN_T 1024
#define SCAN_C 98  // 1024*98 = 100352 >= NODES

__global__ __launch_bounds__(SCAN_T) void scan_kernel(int* __restrict__ counts,
                                                      int* __restrict__ off,
                                                      int* __restrict__ cursor) {
  __shared__ int part[SCAN_T];
  const int t = threadIdx.x;
  const int lo = t * SCAN_C;
  const int hi = (lo + SCAN_C < NODES) ? lo + SCAN_C : NODES;
  int s = 0;
  for (int i = lo; i < hi; ++i) s += counts[i];
  part[t] = s;
  __syncthreads();
  for (int d = 1; d < SCAN_T; d <<= 1) {  // Hillis-Steele inclusive scan
    int v = 0;
    if (t >= d) v = part[t - d];
    __syncthreads();
    if (t >= d) part[t] += v;
    __syncthreads();
  }
  int run = (t == 0) ? 0 : part[t - 1];
  for (int i = lo; i < hi; ++i) {
    const int cn = counts[i];  // read BEFORE cursor write (aliased buffers)
    off[i] = run;
    cursor[i] = run;
    run += cn;
  }
  for (int i = NODES + t; i < NODES + 128; i += SCAN_T) off[i] = EDGES;
}

__global__ __launch_bounds__(256) void scatter_kernel(const int* __restrict__ ei,
                                                      int* __restrict__ cursor,
                                                      uint2* __restrict__ srec) {
  const int t = blockIdx.x * 256 + threadIdx.x;
  if (t < EDGES) {
    int r = ei[t];
    int c = ei[EDGES + t];
    r = (r < 0) ? 0 : ((r >= NODES) ? NODES - 1 : r);
    c = (c < 0) ? 0 : ((c >= NODES) ? NODES - 1 : c);
    const int p = atomicAdd(&cursor[c], 1);
    srec[p] = make_uint2((unsigned)r, (unsigned)c);
  }
}

// ---- main: node-centric, zero global atomics ----
// launch_bounds (256,2): 256-VGPR budget — accumulators must NOT spill
// (round 3: (256,3) capped regs at ~170, spilled accs -> 3.9 GB scratch HBM).
__global__ __launch_bounds__(256, 2) void node_kernel(
    const float* __restrict__ x, const float* __restrict__ pos,
    const unsigned char* __restrict__ ws, float* __restrict__ out) {
  __shared__ uint4 sFeat[2048];                    // 32 KB B-operand frags
  __shared__ __align__(16) float sAccX[NB * 68];   // stride 68: ds-atomic banks ~2-way
  __shared__ float sAccP[NB * 4];
  __shared__ float sRel[ET * 3];
  __shared__ float sDist[ET];
  __shared__ int sLC[ET];
  __shared__ int sRowE[ET];

  const int tid = threadIdx.x;
  const int lane = tid & 63;
  const int wave = tid >> 6;
  const int q = lane >> 4;
  const int nn = lane & 15;
  const int base = blockIdx.x * NB;

  const int* off = (const int*)(ws + WS_OFF);
  const uint2* srec = (const uint2*)(ws + WS_SREC);
  const uint4* wx1f = (const uint4*)(ws + WS_WX1);
  const uint4* wx2f = (const uint4*)(ws + WS_WX2);
  const uint4* wp1f = (const uint4*)(ws + WS_WP1);
  const float* misc = (const float*)(ws + WS_MISC);

  const int e0 = off[base];
  const int e1 = off[base + NB];

  for (int i = tid; i < NB * 68; i += 256) sAccX[i] = 0.f;
  if (tid < NB * 4) sAccP[tid] = 0.f;
  __syncthreads();

  const int et0 = wave * 2;
  const floatx4 fzero = {0.f, 0.f, 0.f, 0.f};

  for (int t0 = e0; t0 < e1; t0 += ET) {
    // ---- phase A: edge records, rel_pos, dist
    if (tid < ET) {
      const int e = t0 + tid;
      int r = 0, lc = 0;
      float r0 = 0.f, r1 = 0.f, r2 = 0.f, dd = 0.f;
      if (e < e1) {
        const uint2 rc = srec[e];
        r = (int)rc.x;
        const int c = (int)rc.y;
        lc = c - base;
        lc = (lc < 0) ? 0 : ((lc > NB - 1) ? NB - 1 : lc);
        r0 = pos[3 * r + 0] - pos[3 * c + 0];
        r1 = pos[3 * r + 1] - pos[3 * c + 1];
        r2 = pos[3 * r + 2] - pos[3 * c + 2];
        dd = r0 * r0 + r1 * r1 + r2 * r2;
      }
      sRowE[tid] = r;
      sLC[tid] = lc;
      sRel[3 * tid + 0] = r0;
      sRel[3 * tid + 1] = r1;
      sRel[3 * tid + 2] = r2;
      sDist[tid] = dd;
    }
    __syncthreads();

    // ---- phase B: x[row] (k 0..63) and x[col] (k 64..127; sorted → L1 hits)
    {
      const int e = tid & (ET - 1);
      const int p = tid >> 7;
      const bool valid = (t0 + e) < e1;
      const int node = p ? (base + sLC[e]) : sRowE[e];
      const float4* src = (const float4*)(x + (size_t)node * 64);
      const int et = e >> 4;
      const int ml = e & 15;
#pragma unroll
      for (int g = 0; g < 8; ++g) {
        float4 a = valid ? src[2 * g + 0] : make_float4(0.f, 0.f, 0.f, 0.f);
        float4 b = valid ? src[2 * g + 1] : make_float4(0.f, 0.f, 0.f, 0.f);
        unsigned int d0 = (unsigned int)f2bf(a.x) | ((unsigned int)f2bf(a.y) << 16);
        unsigned int d1 = (unsigned int)f2bf(a.z) | ((unsigned int)f2bf(a.w) << 16);
        unsigned int d2 = (unsigned int)f2bf(b.x) | ((unsigned int)f2bf(b.y) << 16);
        unsigned int d3 = (unsigned int)f2bf(b.z) | ((unsigned int)f2bf(b.w) << 16);
        const int kf = p * 64 + g * 8;
        const int kt = kf >> 5;
        const int fl = (((kf & 31) >> 3) << 4) | ml;
        sFeat[(et * 4 + kt) * 64 + fl] = make_uint4(d0, d1, d2, d3);
      }
    }
    __syncthreads();

    // ---- phi_pos FIRST (own K-loop): accp live range ends before acc1 starts
    {
      floatx4 accp[2][8];
#pragma unroll
      for (int m = 0; m < 2; ++m)
#pragma unroll
        for (int j = 0; j < 8; ++j) accp[m][j] = fzero;
#pragma unroll
      for (int kt = 0; kt < 2; ++kt) {  // x_row occupies k 0..63
        const short8 b0 = __builtin_bit_cast(short8, sFeat[((et0 + 0) * 4 + kt) * 64 + lane]);
        const short8 b1 = __builtin_bit_cast(short8, sFeat[((et0 + 1) * 4 + kt) * 64 + lane]);
#pragma unroll
        for (int jt = 0; jt < 8; ++jt) {
          const short8 a = __builtin_bit_cast(short8, wp1f[(kt * 8 + jt) * 64 + lane]);
          accp[0][jt] = MFMA(a, b0, accp[0][jt]);
          accp[1][jt] = MFMA(a, b1, accp[1][jt]);
        }
      }
      float wvv[2];
#pragma unroll
      for (int m = 0; m < 2; ++m) {
        float s = 0.f;
#pragma unroll
        for (int jt = 0; jt < 8; ++jt) {
          const float4 bp = *(const float4*)(misc + 192 + jt * 16 + q * 4);
          const float4 wp = *(const float4*)(misc + 320 + jt * 16 + q * 4);
          s += fast_silu(accp[m][jt][0] + bp.x) * wp.x;
          s += fast_silu(accp[m][jt][1] + bp.y) * wp.y;
          s += fast_silu(accp[m][jt][2] + bp.z) * wp.z;
          s += fast_silu(accp[m][jt][3] + bp.w) * wp.w;
        }
        s += __shfl_xor(s, 16);
        s += __shfl_xor(s, 32);
        wvv[m] = s + misc[448];
      }
      if (q == 0) {
#pragma unroll
        for (int m = 0; m < 2; ++m) {
          const int el = (et0 + m) * 16 + nn;
          if (t0 + el < e1) {
            const int lc = sLC[el];
            atomicAdd(&sAccP[lc * 4 + 0], wvv[m] * sRel[3 * el + 0]);
            atomicAdd(&sAccP[lc * 4 + 1], wvv[m] * sRel[3 * el + 1]);
            atomicAdd(&sAccP[lc * 4 + 2], wvv[m] * sRel[3 * el + 2]);
          }
        }
      }
    }

    // ---- GEMM1': h'[j][e] = sum_k Wx1[k][j]*feat[e][k]
    floatx4 acc1[2][8];
#pragma unroll
    for (int m = 0; m < 2; ++m)
#pragma unroll
      for (int j = 0; j < 8; ++j) acc1[m][j] = fzero;
#pragma unroll
    for (int kt = 0; kt < 4; ++kt) {
      const short8 b0 = __builtin_bit_cast(short8, sFeat[((et0 + 0) * 4 + kt) * 64 + lane]);
      const short8 b1 = __builtin_bit_cast(short8, sFeat[((et0 + 1) * 4 + kt) * 64 + lane]);
#pragma unroll
      for (int jt = 0; jt < 8; ++jt) {
        const short8 a = __builtin_bit_cast(short8, wx1f[(kt * 8 + jt) * 64 + lane]);
        acc1[0][jt] = MFMA(a, b0, acc1[0][jt]);
        acc1[1][jt] = MFMA(a, b1, acc1[1][jt]);
      }
    }

    // ---- epilogue 1: h = silu(...) → bf16 B-frags (wave-private sFeat region)
#pragma unroll
    for (int m = 0; m < 2; ++m) {
      const int etG = et0 + m;
      const float dist = sDist[etG * 16 + nn];
#pragma unroll
      for (int jt = 0; jt < 8; ++jt) {
        const float4 bx = *(const float4*)(misc + 0 + jt * 16 + q * 4);
        const float4 wd = *(const float4*)(misc + 456 + jt * 16 + q * 4);
        const unsigned short h0 = f2bf(fast_silu(acc1[m][jt][0] + bx.x + dist * wd.x));
        const unsigned short h1 = f2bf(fast_silu(acc1[m][jt][1] + bx.y + dist * wd.y));
        const unsigned short h2 = f2bf(fast_silu(acc1[m][jt][2] + bx.z + dist * wd.z));
        const unsigned short h3 = f2bf(fast_silu(acc1[m][jt][3] + bx.w + dist * wd.w));
        const int j0 = jt * 16 + q * 4;
        const int kt2 = j0 >> 5;
        const int lane2 = (((j0 & 31) >> 3) << 4) | nn;
        const int byteoff = (j0 & 7) << 1;
        uint2* dst = (uint2*)((char*)sFeat +
                              (((size_t)((etG * 4 + kt2) * 64 + lane2)) << 4) + byteoff);
        *dst = make_uint2((unsigned int)h0 | ((unsigned int)h1 << 16),
                          (unsigned int)h2 | ((unsigned int)h3 << 16));
      }
    }

    // ---- GEMM2': msg'[i][e] = sum_j Wx2[j][i]*h[j][e]
    floatx4 acc2[2][4];
#pragma unroll
    for (int m = 0; m < 2; ++m)
#pragma unroll
      for (int it = 0; it < 4; ++it) acc2[m][it] = fzero;
#pragma unroll
    for (int kt = 0; kt < 4; ++kt) {
      const short8 b0 = __builtin_bit_cast(short8, sFeat[((et0 + 0) * 4 + kt) * 64 + lane]);
      const short8 b1 = __builtin_bit_cast(short8, sFeat[((et0 + 1) * 4 + kt) * 64 + lane]);
#pragma unroll
      for (int it = 0; it < 4; ++it) {
        const short8 a = __builtin_bit_cast(short8, wx2f[(kt * 4 + it) * 64 + lane]);
        acc2[0][it] = MFMA(a, b0, acc2[0][it]);
        acc2[1][it] = MFMA(a, b1, acc2[1][it]);
      }
    }

    // ---- epilogue 2: +bx2 per edge, LDS accumulate per local node
#pragma unroll
    for (int m = 0; m < 2; ++m) {
      const int el = (et0 + m) * 16 + nn;
      const bool v = (t0 + el) < e1;
      const int lc = sLC[el];
      float* arow = sAccX + lc * 68;
#pragma unroll
      for (int it = 0; it < 4; ++it) {
        const float4 b2 = *(const float4*)(misc + 128 + it * 16 + q * 4);
        if (v) {
          const int i0 = it * 16 + q * 4;
          atomicAdd(arow + i0 + 0, acc2[m][it][0] + b2.x);
          atomicAdd(arow + i0 + 1, acc2[m][it][1] + b2.y);
          atomicAdd(arow + i0 + 2, acc2[m][it][2] + b2.z);
          atomicAdd(arow + i0 + 3, acc2[m][it][3] + b2.w);
        }
      }
    }
    __syncthreads();
  }

  // ---- final coalesced stores (no global atomics)
  {
    const int n = base + (tid >> 2);
    if (n < NODES) {
      const int c0 = (tid & 3) * 16;
      float* orow = out + (size_t)n * 64 + c0;
      const float* arow = sAccX + (tid >> 2) * 68 + c0;
#pragma unroll
      for (int j = 0; j < 16; j += 4) *(float4*)(orow + j) = *(const float4*)(arow + j);
    }
    if (tid < 192) {
      const int idx = base * 3 + tid;
      if (idx < NODES * 3)
        out[(size_t)NODES * 64 + idx] = sAccP[(tid / 3) * 4 + (tid % 3)];
    }
  }
}

extern "C" void kernel_launch(void* const* d_in, const int* in_sizes, int n_in,
                              void* d_out, int out_size, void* d_ws, size_t ws_size,
                              hipStream_t stream) {
  (void)in_sizes; (void)n_in; (void)ws_size; (void)out_size;
  const float* x = (const float*)d_in[0];
  const float* pos = (const float*)d_in[1];
  const int* ei = (const int*)d_in[2];
  const float* Wx1 = (const float*)d_in[3];
  const float* bx1 = (const float*)d_in[4];
  const float* Wx2 = (const float*)d_in[5];
  const float* bx2 = (const float*)d_in[6];
  const float* Wp1 = (const float*)d_in[7];
  const float* bp1 = (const float*)d_in[8];
  const float* Wp2 = (const float*)d_in[9];
  const float* bp2 = (const float*)d_in[10];
  float* out = (float*)d_out;
  unsigned char* ws = (unsigned char*)d_ws;

  int* counts = (int*)(ws + WS_CNT);   // aliased with cursor (scan rewrites)
  int* cursor = (int*)(ws + WS_CNT);
  int* off = (int*)(ws + WS_OFF);
  uint2* srec = (uint2*)(ws + WS_SREC);

  hipMemsetAsync(counts, 0, (size_t)NODES * sizeof(int), stream);
  prep_kernel<<<16, 256, 0, stream>>>(Wx1, Wx2, Wp1, bx1, bx2, bp1, Wp2, bp2, ws);
  const int eb = (EDGES + 255) / 256;
  hist_kernel<<<eb, 256, 0, stream>>>(ei, counts);
  scan_kernel<<<1, SCAN_T, 0, stream>>>(counts, off, cursor);
  scatter_kernel<<<eb, 256, 0, stream>>>(ei, cursor, srec);
  node_kernel<<<NBLK, 256, 0, stream>>>(x, pos, ws, out);
}

// Round 5
// 1449.528 us; speedup vs baseline: 1.4246x; 1.0330x over previous
//
#include <hip/hip_runtime.h>

#define EDGES 1000000
#define NODES 100000
#define ET 128   // edges per tile
#define NB 64    // nodes per block (node_kernel)
#define NBLK ((NODES + NB - 1) / NB)  // 1563

typedef short short8 __attribute__((ext_vector_type(8)));
typedef float floatx4 __attribute__((ext_vector_type(4)));
typedef float f32x4 __attribute__((ext_vector_type(4)));     // native vec for nt loads
typedef unsigned int u32x2 __attribute__((ext_vector_type(2)));

#define MFMA(a, b, c) __builtin_amdgcn_mfma_f32_16x16x32_bf16(a, b, c, 0, 0, 0)

// ws layout (bytes)
#define WS_WX1 0        // 32768: Wx1 bf16 frags
#define WS_WX2 32768    // 16384: Wx2 frags
#define WS_WP1 49152    // 16384: Wp1 frags
#define WS_MISC 65536   // 2048: biases etc (floats)
#define WS_OFF 68608    // off[100128] int = 400512 B (CSR offsets, padded)
#define WS_CNT 469504   // counts/cursor[100000] int = 400000 B (aliased)
#define WS_SREC 917504  // uint2[EDGES] = 8 MB sorted (row,col) records
// scan temporaries alias the srec region (they die before scatter writes srec):
#define WS_TMP WS_SREC                 // int[100352] inclusive per-block scans
#define WS_BSUM (WS_SREC + 401408)     // int[98] block sums
#define WS_BSUMX (WS_SREC + 402432)    // int[128] exclusive-scanned block sums

__device__ __forceinline__ unsigned short f2bf(float f) {
  union { float f; unsigned int u; } c;
  c.f = f;
  unsigned int u = c.u;
  u += 0x7fffu + ((u >> 16) & 1u);
  return (unsigned short)(u >> 16);
}

__device__ __forceinline__ float fast_silu(float v) {
#if __has_builtin(__builtin_amdgcn_exp2f) && __has_builtin(__builtin_amdgcn_rcpf)
  float e = __builtin_amdgcn_exp2f(-1.44269504088896340736f * v);
  return v * __builtin_amdgcn_rcpf(1.0f + e);
#else
  return v / (1.0f + __expf(-v));
#endif
}

__global__ __launch_bounds__(256) void prep_kernel(
    const float* __restrict__ Wx1, const float* __restrict__ Wx2,
    const float* __restrict__ Wp1, const float* __restrict__ bx1,
    const float* __restrict__ bx2, const float* __restrict__ bp1,
    const float* __restrict__ Wp2, const float* __restrict__ bp2,
    unsigned char* __restrict__ ws) {
  const int t = blockIdx.x * 256 + threadIdx.x;
  const int nthr = gridDim.x * 256;

  for (int task = t; task < 2048; task += nthr) {  // Wx1[0:128][0:128]
    const int n = task & 127;
    const int kb = task >> 7;
    const int k0 = kb << 3;
    unsigned int d[4];
#pragma unroll
    for (int i = 0; i < 4; ++i) {
      unsigned short lo = f2bf(Wx1[(k0 + 2 * i) * 128 + n]);
      unsigned short hi = f2bf(Wx1[(k0 + 2 * i + 1) * 128 + n]);
      d[i] = (unsigned int)lo | ((unsigned int)hi << 16);
    }
    const int lane = ((kb & 3) << 4) | (n & 15);
    const int frag = ((kb >> 2) << 3) | (n >> 4);
    *(uint4*)(ws + WS_WX1 + ((size_t)(frag * 64 + lane) << 4)) =
        make_uint4(d[0], d[1], d[2], d[3]);
  }
  for (int task = t; task < 1024; task += nthr) {  // Wx2[0:128][0:64]
    const int n = task & 63;
    const int kb = task >> 6;
    const int k0 = kb << 3;
    unsigned int d[4];
#pragma unroll
    for (int i = 0; i < 4; ++i) {
      unsigned short lo = f2bf(Wx2[(k0 + 2 * i) * 64 + n]);
      unsigned short hi = f2bf(Wx2[(k0 + 2 * i + 1) * 64 + n]);
      d[i] = (unsigned int)lo | ((unsigned int)hi << 16);
    }
    const int lane = ((kb & 3) << 4) | (n & 15);
    const int frag = ((kb >> 2) << 2) | (n >> 4);
    *(uint4*)(ws + WS_WX2 + ((size_t)(frag * 64 + lane) << 4)) =
        make_uint4(d[0], d[1], d[2], d[3]);
  }
  for (int task = t; task < 1024; task += nthr) {  // Wp1[0:64][0:128]
    const int n = task & 127;
    const int kb = task >> 7;
    const int k0 = kb << 3;
    unsigned int d[4];
#pragma unroll
    for (int i = 0; i < 4; ++i) {
      unsigned short lo = f2bf(Wp1[(k0 + 2 * i) * 128 + n]);
      unsigned short hi = f2bf(Wp1[(k0 + 2 * i + 1) * 128 + n]);
      d[i] = (unsigned int)lo | ((unsigned int)hi << 16);
    }
    const int lane = ((kb & 3) << 4) | (n & 15);
    const int frag = ((kb >> 2) << 3) | (n >> 4);
    *(uint4*)(ws + WS_WP1 + ((size_t)(frag * 64 + lane) << 4)) =
        make_uint4(d[0], d[1], d[2], d[3]);
  }
  float* misc = (float*)(ws + WS_MISC);
  for (int i = t; i < 128; i += nthr) misc[i] = bx1[i];
  for (int i = t; i < 64; i += nthr) misc[128 + i] = bx2[i];
  for (int i = t; i < 128; i += nthr) misc[192 + i] = bp1[i];
  for (int i = t; i < 128; i += nthr) misc[320 + i] = Wp2[i];
  if (t == 0) misc[448] = bp2[0];
  for (int i = t; i < 128; i += nthr) misc[456 + i] = Wx1[128 * 128 + i];
}

// ---- counting sort by col ----
__global__ __launch_bounds__(256) void hist_kernel(const int* __restrict__ ei,
                                                   int* __restrict__ counts) {
  const int t = blockIdx.x * 256 + threadIdx.x;
  if (t < EDGES) {
    int c = __builtin_nontemporal_load(ei + EDGES + t);
    c = (c < 0) ? 0 : ((c >= NODES) ? NODES - 1 : c);
    atomicAdd(&counts[c], 1);
  }
}

// 3-kernel coalesced scan over 100k counts (round-4 single-block scan was a
// serial 1-CU bottleneck inside the 374 us non-node overhead).
#define SCB 98  // blocks of 1024: 98*1024 = 100352 >= NODES+128

__global__ __launch_bounds__(1024) void scan1_kernel(const int* __restrict__ counts,
                                                     int* __restrict__ tmp,
                                                     int* __restrict__ bsum) {
  __shared__ int part[1024];
  const int t = threadIdx.x;
  const int i = blockIdx.x * 1024 + t;
  int v = (i < NODES) ? counts[i] : 0;
  part[t] = v;
  __syncthreads();
  for (int d = 1; d < 1024; d <<= 1) {
    int u = 0;
    if (t >= d) u = part[t - d];
    __syncthreads();
    if (t >= d) part[t] += u;
    __syncthreads();
  }
  tmp[i] = part[t];  // inclusive scan within block
  if (t == 1023) bsum[blockIdx.x] = part[1023];
}

__global__ __launch_bounds__(128) void scan2_kernel(const int* __restrict__ bsum,
                                                    int* __restrict__ bsumx) {
  __shared__ int part[128];
  const int t = threadIdx.x;
  int v = (t < SCB) ? bsum[t] : 0;
  part[t] = v;
  __syncthreads();
  for (int d = 1; d < 128; d <<= 1) {
    int u = 0;
    if (t >= d) u = part[t - d];
    __syncthreads();
    if (t >= d) part[t] += u;
    __syncthreads();
  }
  bsumx[t] = part[t] - v;  // exclusive
}

__global__ __launch_bounds__(1024) void scan3_kernel(const int* __restrict__ counts,
                                                     const int* __restrict__ tmp,
                                                     const int* __restrict__ bsumx,
                                                     int* __restrict__ off,
                                                     int* __restrict__ cursor) {
  const int i = blockIdx.x * 1024 + threadIdx.x;
  if (i < NODES) {
    const int cn = counts[i];  // read before cursor write (aliased with counts)
    const int o = bsumx[blockIdx.x] + tmp[i] - cn;
    off[i] = o;
    cursor[i] = o;
  } else if (i < NODES + 128) {
    off[i] = EDGES;
  }
}

__global__ __launch_bounds__(256) void scatter_kernel(const int* __restrict__ ei,
                                                      int* __restrict__ cursor,
                                                      unsigned int* __restrict__ srec) {
  const int t = blockIdx.x * 256 + threadIdx.x;
  if (t < EDGES) {
    int r = __builtin_nontemporal_load(ei + t);
    int c = __builtin_nontemporal_load(ei + EDGES + t);
    r = (r < 0) ? 0 : ((r >= NODES) ? NODES - 1 : r);
    c = (c < 0) ? 0 : ((c >= NODES) ? NODES - 1 : c);
    const int p = atomicAdd(&cursor[c], 1);
    u32x2 rec;
    rec[0] = (unsigned)r;
    rec[1] = (unsigned)c;
    __builtin_nontemporal_store(rec, (u32x2*)(srec + 2 * (size_t)p));
  }
}

// ---- main: node-centric, zero global atomics ----
// (256,2): 256-VGPR budget. One-etile-at-a-time scopes keep peak live
// accumulators at 32 regs (r4's m-paired scopes still spilled: 489 MB
// scratch writes, 1.1 GB scratch reads at VGPR_Count=128).
__global__ __launch_bounds__(256, 2) void node_kernel(
    const float* __restrict__ x, const float* __restrict__ pos,
    const unsigned char* __restrict__ ws, float* __restrict__ out) {
  __shared__ uint4 sFeat[2048];                    // 32 KB B-operand frags
  __shared__ __align__(16) float sAccX[NB * 68];   // stride 68: ds-atomic banks ~2-way
  __shared__ float sAccP[NB * 4];
  __shared__ float sRel[ET * 3];
  __shared__ float sDist[ET];
  __shared__ int sLC[ET];
  __shared__ int sRowE[ET];

  const int tid = threadIdx.x;
  const int lane = tid & 63;
  const int wave = tid >> 6;
  const int q = lane >> 4;
  const int nn = lane & 15;
  const int base = blockIdx.x * NB;

  const int* off = (const int*)(ws + WS_OFF);
  const unsigned int* srec = (const unsigned int*)(ws + WS_SREC);
  const uint4* wx1f = (const uint4*)(ws + WS_WX1);
  const uint4* wx2f = (const uint4*)(ws + WS_WX2);
  const uint4* wp1f = (const uint4*)(ws + WS_WP1);
  const float* misc = (const float*)(ws + WS_MISC);

  const int e0 = off[base];
  const int e1 = off[base + NB];

  for (int i = tid; i < NB * 68; i += 256) sAccX[i] = 0.f;
  if (tid < NB * 4) sAccP[tid] = 0.f;
  __syncthreads();

  const int et0 = wave * 2;
  const floatx4 fzero = {0.f, 0.f, 0.f, 0.f};

  for (int t0 = e0; t0 < e1; t0 += ET) {
    // ---- phase A: edge records, rel_pos, dist
    if (tid < ET) {
      const int e = t0 + tid;
      int r = 0, lc = 0;
      float r0 = 0.f, r1 = 0.f, r2 = 0.f, dd = 0.f;
      if (e < e1) {
        const u32x2 rc = __builtin_nontemporal_load((const u32x2*)(srec + 2 * (size_t)e));
        r = (int)rc[0];
        const int c = (int)rc[1];
        lc = c - base;
        lc = (lc < 0) ? 0 : ((lc > NB - 1) ? NB - 1 : lc);
        r0 = pos[3 * r + 0] - pos[3 * c + 0];
        r1 = pos[3 * r + 1] - pos[3 * c + 1];
        r2 = pos[3 * r + 2] - pos[3 * c + 2];
        dd = r0 * r0 + r1 * r1 + r2 * r2;
      }
      sRowE[tid] = r;
      sLC[tid] = lc;
      sRel[3 * tid + 0] = r0;
      sRel[3 * tid + 1] = r1;
      sRel[3 * tid + 2] = r2;
      sDist[tid] = dd;
    }
    __syncthreads();

    // ---- phase B: x[row] (k 0..63, nt: protect L2) and x[col] (k 64..127, sorted)
    {
      const int e = tid & (ET - 1);
      const int p = tid >> 7;
      const bool valid = (t0 + e) < e1;
      const int node = p ? (base + sLC[e]) : sRowE[e];
      const f32x4* src = (const f32x4*)(x + (size_t)node * 64);
      const int et = e >> 4;
      const int ml = e & 15;
      const f32x4 vz = {0.f, 0.f, 0.f, 0.f};
#pragma unroll
      for (int g = 0; g < 8; ++g) {
        f32x4 a, b;
        if (valid) {
          if (p) {  // col: reused within block -> cached
            a = src[2 * g + 0];
            b = src[2 * g + 1];
          } else {  // row: random stream -> nontemporal
            a = __builtin_nontemporal_load(src + 2 * g + 0);
            b = __builtin_nontemporal_load(src + 2 * g + 1);
          }
        } else {
          a = vz;
          b = vz;
        }
        unsigned int d0 = (unsigned int)f2bf(a[0]) | ((unsigned int)f2bf(a[1]) << 16);
        unsigned int d1 = (unsigned int)f2bf(a[2]) | ((unsigned int)f2bf(a[3]) << 16);
        unsigned int d2 = (unsigned int)f2bf(b[0]) | ((unsigned int)f2bf(b[1]) << 16);
        unsigned int d3 = (unsigned int)f2bf(b[2]) | ((unsigned int)f2bf(b[3]) << 16);
        const int kf = p * 64 + g * 8;
        const int kt = kf >> 5;
        const int fl = (((kf & 31) >> 3) << 4) | ml;
        sFeat[(et * 4 + kt) * 64 + fl] = make_uint4(d0, d1, d2, d3);
      }
    }
    __syncthreads();

    // ---- phi_pos, one etile at a time (accp[8] = 32 regs peak)
    float wvv[2];
#pragma unroll
    for (int m = 0; m < 2; ++m) {
      floatx4 accp[8];
#pragma unroll
      for (int j = 0; j < 8; ++j) accp[j] = fzero;
#pragma unroll
      for (int kt = 0; kt < 2; ++kt) {  // x_row occupies k 0..63
        const short8 b = __builtin_bit_cast(short8, sFeat[((et0 + m) * 4 + kt) * 64 + lane]);
#pragma unroll
        for (int jt = 0; jt < 8; ++jt) {
          const short8 a = __builtin_bit_cast(short8, wp1f[(kt * 8 + jt) * 64 + lane]);
          accp[jt] = MFMA(a, b, accp[jt]);
        }
      }
      float s = 0.f;
#pragma unroll
      for (int jt = 0; jt < 8; ++jt) {
        const float4 bp = *(const float4*)(misc + 192 + jt * 16 + q * 4);
        const float4 wp = *(const float4*)(misc + 320 + jt * 16 + q * 4);
        s += fast_silu(accp[jt][0] + bp.x) * wp.x;
        s += fast_silu(accp[jt][1] + bp.y) * wp.y;
        s += fast_silu(accp[jt][2] + bp.z) * wp.z;
        s += fast_silu(accp[jt][3] + bp.w) * wp.w;
      }
      s += __shfl_xor(s, 16);
      s += __shfl_xor(s, 32);
      wvv[m] = s + misc[448];
    }
    if (q == 0) {
#pragma unroll
      for (int m = 0; m < 2; ++m) {
        const int el = (et0 + m) * 16 + nn;
        if (t0 + el < e1) {
          const int lc = sLC[el];
          atomicAdd(&sAccP[lc * 4 + 0], wvv[m] * sRel[3 * el + 0]);
          atomicAdd(&sAccP[lc * 4 + 1], wvv[m] * sRel[3 * el + 1]);
          atomicAdd(&sAccP[lc * 4 + 2], wvv[m] * sRel[3 * el + 2]);
        }
      }
    }

    // ---- GEMM1 + epilogue 1, one etile at a time (acc1[8] = 32 regs peak)
#pragma unroll
    for (int m = 0; m < 2; ++m) {
      floatx4 acc1[8];
#pragma unroll
      for (int j = 0; j < 8; ++j) acc1[j] = fzero;
#pragma unroll
      for (int kt = 0; kt < 4; ++kt) {
        const short8 b = __builtin_bit_cast(short8, sFeat[((et0 + m) * 4 + kt) * 64 + lane]);
#pragma unroll
        for (int jt = 0; jt < 8; ++jt) {
          const short8 a = __builtin_bit_cast(short8, wx1f[(kt * 8 + jt) * 64 + lane]);
          acc1[jt] = MFMA(a, b, acc1[jt]);
        }
      }
      const int etG = et0 + m;
      const float dist = sDist[etG * 16 + nn];
#pragma unroll
      for (int jt = 0; jt < 8; ++jt) {
        const float4 bx = *(const float4*)(misc + 0 + jt * 16 + q * 4);
        const float4 wd = *(const float4*)(misc + 456 + jt * 16 + q * 4);
        const unsigned short h0 = f2bf(fast_silu(acc1[jt][0] + bx.x + dist * wd.x));
        const unsigned short h1 = f2bf(fast_silu(acc1[jt][1] + bx.y + dist * wd.y));
        const unsigned short h2 = f2bf(fast_silu(acc1[jt][2] + bx.z + dist * wd.z));
        const unsigned short h3 = f2bf(fast_silu(acc1[jt][3] + bx.w + dist * wd.w));
        const int j0 = jt * 16 + q * 4;
        const int kt2 = j0 >> 5;
        const int lane2 = (((j0 & 31) >> 3) << 4) | nn;
        const int byteoff = (j0 & 7) << 1;
        uint2* dst = (uint2*)((char*)sFeat +
                              (((size_t)((etG * 4 + kt2) * 64 + lane2)) << 4) + byteoff);
        *dst = make_uint2((unsigned int)h0 | ((unsigned int)h1 << 16),
                          (unsigned int)h2 | ((unsigned int)h3 << 16));
      }
    }

    // ---- GEMM2 + epilogue 2, one etile at a time (acc2[4] = 16 regs peak)
#pragma unroll
    for (int m = 0; m < 2; ++m) {
      floatx4 acc2[4];
#pragma unroll
      for (int it = 0; it < 4; ++it) acc2[it] = fzero;
#pragma unroll
      for (int kt = 0; kt < 4; ++kt) {
        const short8 b = __builtin_bit_cast(short8, sFeat[((et0 + m) * 4 + kt) * 64 + lane]);
#pragma unroll
        for (int it = 0; it < 4; ++it) {
          const short8 a = __builtin_bit_cast(short8, wx2f[(kt * 4 + it) * 64 + lane]);
          acc2[it] = MFMA(a, b, acc2[it]);
        }
      }
      const int el = (et0 + m) * 16 + nn;
      const bool v = (t0 + el) < e1;
      const int lc = sLC[el];
      float* arow = sAccX + lc * 68;
#pragma unroll
      for (int it = 0; it < 4; ++it) {
        const float4 b2 = *(const float4*)(misc + 128 + it * 16 + q * 4);
        if (v) {
          const int i0 = it * 16 + q * 4;
          atomicAdd(arow + i0 + 0, acc2[it][0] + b2.x);
          atomicAdd(arow + i0 + 1, acc2[it][1] + b2.y);
          atomicAdd(arow + i0 + 2, acc2[it][2] + b2.z);
          atomicAdd(arow + i0 + 3, acc2[it][3] + b2.w);
        }
      }
    }
    __syncthreads();
  }

  // ---- final coalesced stores (no global atomics)
  {
    const int n = base + (tid >> 2);
    if (n < NODES) {
      const int c0 = (tid & 3) * 16;
      float* orow = out + (size_t)n * 64 + c0;
      const float* arow = sAccX + (tid >> 2) * 68 + c0;
#pragma unroll
      for (int j = 0; j < 16; j += 4) *(float4*)(orow + j) = *(const float4*)(arow + j);
    }
    if (tid < 192) {
      const int idx = base * 3 + tid;
      if (idx < NODES * 3)
        out[(size_t)NODES * 64 + idx] = sAccP[(tid / 3) * 4 + (tid % 3)];
    }
  }
}

extern "C" void kernel_launch(void* const* d_in, const int* in_sizes, int n_in,
                              void* d_out, int out_size, void* d_ws, size_t ws_size,
                              hipStream_t stream) {
  (void)in_sizes; (void)n_in; (void)ws_size; (void)out_size;
  const float* x = (const float*)d_in[0];
  const float* pos = (const float*)d_in[1];
  const int* ei = (const int*)d_in[2];
  const float* Wx1 = (const float*)d_in[3];
  const float* bx1 = (const float*)d_in[4];
  const float* Wx2 = (const float*)d_in[5];
  const float* bx2 = (const float*)d_in[6];
  const float* Wp1 = (const float*)d_in[7];
  const float* bp1 = (const float*)d_in[8];
  const float* Wp2 = (const float*)d_in[9];
  const float* bp2 = (const float*)d_in[10];
  float* out = (float*)d_out;
  unsigned char* ws = (unsigned char*)d_ws;

  int* counts = (int*)(ws + WS_CNT);   // aliased with cursor (scan3 rewrites)
  int* cursor = (int*)(ws + WS_CNT);
  int* off = (int*)(ws + WS_OFF);
  int* tmp = (int*)(ws + WS_TMP);      // aliased with srec (dies before scatter)
  int* bsum = (int*)(ws + WS_BSUM);
  int* bsumx = (int*)(ws + WS_BSUMX);
  unsigned int* srec = (unsigned int*)(ws + WS_SREC);

  hipMemsetAsync(counts, 0, (size_t)NODES * sizeof(int), stream);
  prep_kernel<<<16, 256, 0, stream>>>(Wx1, Wx2, Wp1, bx1, bx2, bp1, Wp2, bp2, ws);
  const int eb = (EDGES + 255) / 256;
  hist_kernel<<<eb, 256, 0, stream>>>(ei, counts);
  scan1_kernel<<<SCB, 1024, 0, stream>>>(counts, tmp, bsum);
  scan2_kernel<<<1, 128, 0, stream>>>(bsum, bsumx);
  scan3_kernel<<<SCB, 1024, 0, stream>>>(counts, tmp, bsumx, off, cursor);
  scatter_kernel<<<eb, 256, 0, stream>>>(ei, cursor, srec);
  node_kernel<<<NBLK, 256, 0, stream>>>(x, pos, ws, out);
}

// Round 6
// 960.888 us; speedup vs baseline: 2.1490x; 1.5085x over previous
//
#include <hip/hip_runtime.h>

#define EDGES 1000000
#define NODES 100000
#define ET 128   // edges per tile
#define NB 64    // nodes per block (node_kernel)
#define NBLK ((NODES + NB - 1) / NB)  // 1563

typedef short short8 __attribute__((ext_vector_type(8)));
typedef float floatx4 __attribute__((ext_vector_type(4)));
typedef unsigned int u32x2 __attribute__((ext_vector_type(2)));

#define MFMA(a, b, c) __builtin_amdgcn_mfma_f32_16x16x32_bf16(a, b, c, 0, 0, 0)

// ws layout (bytes)
#define WS_WX1 0        // 32768: Wx1 bf16 frags
#define WS_WX2 32768    // 16384: Wx2 frags
#define WS_WP1 49152    // 16384: Wp1 frags
#define WS_MISC 65536   // 2048: biases etc (floats)
#define WS_OFF 68608    // off[100128] int = 400512 B (CSR offsets, padded)
#define WS_CNT 469504   // counts/cursor[100000] int = 400000 B (aliased)
#define WS_SREC 917504  // uint2[EDGES] = 8 MB sorted (row,col) records
// scan temporaries alias the srec region (they die before scatter writes srec):
#define WS_TMP WS_SREC                 // int[100352] inclusive per-block scans
#define WS_BSUM (WS_SREC + 401408)     // int[98] block sums
#define WS_BSUMX (WS_SREC + 402432)    // int[128] exclusive-scanned block sums

__device__ __forceinline__ unsigned short f2bf(float f) {
  union { float f; unsigned int u; } c;
  c.f = f;
  unsigned int u = c.u;
  u += 0x7fffu + ((u >> 16) & 1u);
  return (unsigned short)(u >> 16);
}

__device__ __forceinline__ float fast_silu(float v) {
#if __has_builtin(__builtin_amdgcn_exp2f) && __has_builtin(__builtin_amdgcn_rcpf)
  float e = __builtin_amdgcn_exp2f(-1.44269504088896340736f * v);
  return v * __builtin_amdgcn_rcpf(1.0f + e);
#else
  return v / (1.0f + __expf(-v));
#endif
}

__global__ __launch_bounds__(256) void prep_kernel(
    const float* __restrict__ Wx1, const float* __restrict__ Wx2,
    const float* __restrict__ Wp1, const float* __restrict__ bx1,
    const float* __restrict__ bx2, const float* __restrict__ bp1,
    const float* __restrict__ Wp2, const float* __restrict__ bp2,
    unsigned char* __restrict__ ws) {
  const int t = blockIdx.x * 256 + threadIdx.x;
  const int nthr = gridDim.x * 256;

  for (int task = t; task < 2048; task += nthr) {  // Wx1[0:128][0:128]
    const int n = task & 127;
    const int kb = task >> 7;
    const int k0 = kb << 3;
    unsigned int d[4];
#pragma unroll
    for (int i = 0; i < 4; ++i) {
      unsigned short lo = f2bf(Wx1[(k0 + 2 * i) * 128 + n]);
      unsigned short hi = f2bf(Wx1[(k0 + 2 * i + 1) * 128 + n]);
      d[i] = (unsigned int)lo | ((unsigned int)hi << 16);
    }
    const int lane = ((kb & 3) << 4) | (n & 15);
    const int frag = ((kb >> 2) << 3) | (n >> 4);
    *(uint4*)(ws + WS_WX1 + ((size_t)(frag * 64 + lane) << 4)) =
        make_uint4(d[0], d[1], d[2], d[3]);
  }
  for (int task = t; task < 1024; task += nthr) {  // Wx2[0:128][0:64]
    const int n = task & 63;
    const int kb = task >> 6;
    const int k0 = kb << 3;
    unsigned int d[4];
#pragma unroll
    for (int i = 0; i < 4; ++i) {
      unsigned short lo = f2bf(Wx2[(k0 + 2 * i) * 64 + n]);
      unsigned short hi = f2bf(Wx2[(k0 + 2 * i + 1) * 64 + n]);
      d[i] = (unsigned int)lo | ((unsigned int)hi << 16);
    }
    const int lane = ((kb & 3) << 4) | (n & 15);
    const int frag = ((kb >> 2) << 2) | (n >> 4);
    *(uint4*)(ws + WS_WX2 + ((size_t)(frag * 64 + lane) << 4)) =
        make_uint4(d[0], d[1], d[2], d[3]);
  }
  for (int task = t; task < 1024; task += nthr) {  // Wp1[0:64][0:128]
    const int n = task & 127;
    const int kb = task >> 7;
    const int k0 = kb << 3;
    unsigned int d[4];
#pragma unroll
    for (int i = 0; i < 4; ++i) {
      unsigned short lo = f2bf(Wp1[(k0 + 2 * i) * 128 + n]);
      unsigned short hi = f2bf(Wp1[(k0 + 2 * i + 1) * 128 + n]);
      d[i] = (unsigned int)lo | ((unsigned int)hi << 16);
    }
    const int lane = ((kb & 3) << 4) | (n & 15);
    const int frag = ((kb >> 2) << 3) | (n >> 4);
    *(uint4*)(ws + WS_WP1 + ((size_t)(frag * 64 + lane) << 4)) =
        make_uint4(d[0], d[1], d[2], d[3]);
  }
  float* misc = (float*)(ws + WS_MISC);
  for (int i = t; i < 128; i += nthr) misc[i] = bx1[i];
  for (int i = t; i < 64; i += nthr) misc[128 + i] = bx2[i];
  for (int i = t; i < 128; i += nthr) misc[192 + i] = bp1[i];
  for (int i = t; i < 128; i += nthr) misc[320 + i] = Wp2[i];
  if (t == 0) misc[448] = bp2[0];
  for (int i = t; i < 128; i += nthr) misc[456 + i] = Wx1[128 * 128 + i];
}

// ---- counting sort by col ----
__global__ __launch_bounds__(256) void hist_kernel(const int* __restrict__ ei,
                                                   int* __restrict__ counts) {
  const int t = blockIdx.x * 256 + threadIdx.x;
  if (t < EDGES) {
    int c = __builtin_nontemporal_load(ei + EDGES + t);
    c = (c < 0) ? 0 : ((c >= NODES) ? NODES - 1 : c);
    atomicAdd(&counts[c], 1);
  }
}

#define SCB 98  // blocks of 1024: 98*1024 = 100352 >= NODES+128

__global__ __launch_bounds__(1024) void scan1_kernel(const int* __restrict__ counts,
                                                     int* __restrict__ tmp,
                                                     int* __restrict__ bsum) {
  __shared__ int part[1024];
  const int t = threadIdx.x;
  const int i = blockIdx.x * 1024 + t;
  int v = (i < NODES) ? counts[i] : 0;
  part[t] = v;
  __syncthreads();
  for (int d = 1; d < 1024; d <<= 1) {
    int u = 0;
    if (t >= d) u = part[t - d];
    __syncthreads();
    if (t >= d) part[t] += u;
    __syncthreads();
  }
  tmp[i] = part[t];  // inclusive scan within block
  if (t == 1023) bsum[blockIdx.x] = part[1023];
}

__global__ __launch_bounds__(128) void scan2_kernel(const int* __restrict__ bsum,
                                                    int* __restrict__ bsumx) {
  __shared__ int part[128];
  const int t = threadIdx.x;
  int v = (t < SCB) ? bsum[t] : 0;
  part[t] = v;
  __syncthreads();
  for (int d = 1; d < 128; d <<= 1) {
    int u = 0;
    if (t >= d) u = part[t - d];
    __syncthreads();
    if (t >= d) part[t] += u;
    __syncthreads();
  }
  bsumx[t] = part[t] - v;  // exclusive
}

__global__ __launch_bounds__(1024) void scan3_kernel(const int* __restrict__ counts,
                                                     const int* __restrict__ tmp,
                                                     const int* __restrict__ bsumx,
                                                     int* __restrict__ off,
                                                     int* __restrict__ cursor) {
  const int i = blockIdx.x * 1024 + threadIdx.x;
  if (i < NODES) {
    const int cn = counts[i];  // read before cursor write (aliased with counts)
    const int o = bsumx[blockIdx.x] + tmp[i] - cn;
    off[i] = o;
    cursor[i] = o;
  } else if (i < NODES + 128) {
    off[i] = EDGES;
  }
}

__global__ __launch_bounds__(256) void scatter_kernel(const int* __restrict__ ei,
                                                      int* __restrict__ cursor,
                                                      unsigned int* __restrict__ srec) {
  const int t = blockIdx.x * 256 + threadIdx.x;
  if (t < EDGES) {
    int r = __builtin_nontemporal_load(ei + t);
    int c = __builtin_nontemporal_load(ei + EDGES + t);
    r = (r < 0) ? 0 : ((r >= NODES) ? NODES - 1 : r);
    c = (c < 0) ? 0 : ((c >= NODES) ? NODES - 1 : c);
    const int p = atomicAdd(&cursor[c], 1);
    // plain (cached) store: scattered 8B nt stores would write-amplify at
    // 64B granule; L2 write-combines these instead.
    srec[2 * (size_t)p] = (unsigned)r;
    srec[2 * (size_t)p + 1] = (unsigned)c;
  }
}

// ---- main: node-centric, zero global atomics ----
// Spill control (r3/r4/r5 lesson): the register cap doesn't stop the
// SCHEDULER from hoisting 32-64 global A-frag loads ahead of the MFMAs;
// that hoisting is what spilled (~1.1 GB scratch reads/round). unroll(1)
// on tile/etile/kt loops keeps <=8 A-frag loads in flight (~32 VGPRs).
__global__ __launch_bounds__(256, 2) void node_kernel(
    const float* __restrict__ x, const float* __restrict__ pos,
    const unsigned char* __restrict__ ws, float* __restrict__ out) {
  __shared__ uint4 sFeat[2048];                    // 32 KB B-operand frags
  __shared__ __align__(16) float sAccX[NB * 68];   // stride 68: ds-atomic banks ~2-way
  __shared__ float sAccP[NB * 4];
  __shared__ float sRel[ET * 3];
  __shared__ float sDist[ET];
  __shared__ int sLC[ET];
  __shared__ int sRowE[ET];

  const int tid = threadIdx.x;
  const int lane = tid & 63;
  const int wave = tid >> 6;
  const int q = lane >> 4;
  const int nn = lane & 15;
  const int base = blockIdx.x * NB;

  const int* off = (const int*)(ws + WS_OFF);
  const unsigned int* srec = (const unsigned int*)(ws + WS_SREC);
  const uint4* wx1f = (const uint4*)(ws + WS_WX1);
  const uint4* wx2f = (const uint4*)(ws + WS_WX2);
  const uint4* wp1f = (const uint4*)(ws + WS_WP1);
  const float* misc = (const float*)(ws + WS_MISC);

  const int e0 = off[base];
  const int e1 = off[base + NB];

  for (int i = tid; i < NB * 68; i += 256) sAccX[i] = 0.f;
  if (tid < NB * 4) sAccP[tid] = 0.f;
  __syncthreads();

  const int et0 = wave * 2;
  const floatx4 fzero = {0.f, 0.f, 0.f, 0.f};

#pragma unroll 1
  for (int t0 = e0; t0 < e1; t0 += ET) {
    // ---- phase A: edge records, rel_pos, dist
    if (tid < ET) {
      const int e = t0 + tid;
      int r = 0, lc = 0;
      float r0 = 0.f, r1 = 0.f, r2 = 0.f, dd = 0.f;
      if (e < e1) {
        const u32x2 rc = *(const u32x2*)(srec + 2 * (size_t)e);
        r = (int)rc[0];
        const int c = (int)rc[1];
        lc = c - base;
        lc = (lc < 0) ? 0 : ((lc > NB - 1) ? NB - 1 : lc);
        r0 = pos[3 * r + 0] - pos[3 * c + 0];
        r1 = pos[3 * r + 1] - pos[3 * c + 1];
        r2 = pos[3 * r + 2] - pos[3 * c + 2];
        dd = r0 * r0 + r1 * r1 + r2 * r2;
      }
      sRowE[tid] = r;
      sLC[tid] = lc;
      sRel[3 * tid + 0] = r0;
      sRel[3 * tid + 1] = r1;
      sRel[3 * tid + 2] = r2;
      sDist[tid] = dd;
    }
    __syncthreads();

    // ---- phase B: gather x rows -> bf16 B-frags (plain cached loads)
    {
      const int e = tid & (ET - 1);
      const int p = tid >> 7;
      const bool valid = (t0 + e) < e1;
      const int node = p ? (base + sLC[e]) : sRowE[e];
      const float4* src = (const float4*)(x + (size_t)node * 64);
      const int et = e >> 4;
      const int ml = e & 15;
#pragma unroll 1
      for (int g = 0; g < 8; ++g) {
        float4 a = valid ? src[2 * g + 0] : make_float4(0.f, 0.f, 0.f, 0.f);
        float4 b = valid ? src[2 * g + 1] : make_float4(0.f, 0.f, 0.f, 0.f);
        unsigned int d0 = (unsigned int)f2bf(a.x) | ((unsigned int)f2bf(a.y) << 16);
        unsigned int d1 = (unsigned int)f2bf(a.z) | ((unsigned int)f2bf(a.w) << 16);
        unsigned int d2 = (unsigned int)f2bf(b.x) | ((unsigned int)f2bf(b.y) << 16);
        unsigned int d3 = (unsigned int)f2bf(b.z) | ((unsigned int)f2bf(b.w) << 16);
        const int kf = p * 64 + g * 8;
        const int kt = kf >> 5;
        const int fl = (((kf & 31) >> 3) << 4) | ml;
        sFeat[(et * 4 + kt) * 64 + fl] = make_uint4(d0, d1, d2, d3);
      }
    }
    __syncthreads();

#pragma unroll 1
    for (int mm = 0; mm < 2; ++mm) {
      const int etG = et0 + mm;

      // ---- phi_pos (accp[8] = 32 regs peak; kt rolled: <=8 loads in flight)
      {
        floatx4 accp[8];
#pragma unroll
        for (int j = 0; j < 8; ++j) accp[j] = fzero;
#pragma unroll 1
        for (int kt = 0; kt < 2; ++kt) {  // x_row occupies k 0..63
          const short8 b = __builtin_bit_cast(short8, sFeat[(etG * 4 + kt) * 64 + lane]);
#pragma unroll
          for (int jt = 0; jt < 8; ++jt) {
            const short8 a = __builtin_bit_cast(short8, wp1f[(kt * 8 + jt) * 64 + lane]);
            accp[jt] = MFMA(a, b, accp[jt]);
          }
        }
        float s = 0.f;
#pragma unroll
        for (int jt = 0; jt < 8; ++jt) {
          const float4 bp = *(const float4*)(misc + 192 + jt * 16 + q * 4);
          const float4 wp = *(const float4*)(misc + 320 + jt * 16 + q * 4);
          s += fast_silu(accp[jt][0] + bp.x) * wp.x;
          s += fast_silu(accp[jt][1] + bp.y) * wp.y;
          s += fast_silu(accp[jt][2] + bp.z) * wp.z;
          s += fast_silu(accp[jt][3] + bp.w) * wp.w;
        }
        s += __shfl_xor(s, 16);
        s += __shfl_xor(s, 32);
        const float wv = s + misc[448];
        if (q == 0) {
          const int el = etG * 16 + nn;
          if (t0 + el < e1) {
            const int lc = sLC[el];
            atomicAdd(&sAccP[lc * 4 + 0], wv * sRel[3 * el + 0]);
            atomicAdd(&sAccP[lc * 4 + 1], wv * sRel[3 * el + 1]);
            atomicAdd(&sAccP[lc * 4 + 2], wv * sRel[3 * el + 2]);
          }
        }
      }

      // ---- GEMM1 + epilogue 1 (acc1[8] = 32 regs peak)
      {
        floatx4 acc1[8];
#pragma unroll
        for (int j = 0; j < 8; ++j) acc1[j] = fzero;
#pragma unroll 1
        for (int kt = 0; kt < 4; ++kt) {
          const short8 b = __builtin_bit_cast(short8, sFeat[(etG * 4 + kt) * 64 + lane]);
#pragma unroll
          for (int jt = 0; jt < 8; ++jt) {
            const short8 a = __builtin_bit_cast(short8, wx1f[(kt * 8 + jt) * 64 + lane]);
            acc1[jt] = MFMA(a, b, acc1[jt]);
          }
        }
        const float dist = sDist[etG * 16 + nn];
#pragma unroll
        for (int jt = 0; jt < 8; ++jt) {
          const float4 bx = *(const float4*)(misc + 0 + jt * 16 + q * 4);
          const float4 wd = *(const float4*)(misc + 456 + jt * 16 + q * 4);
          const unsigned short h0 = f2bf(fast_silu(acc1[jt][0] + bx.x + dist * wd.x));
          const unsigned short h1 = f2bf(fast_silu(acc1[jt][1] + bx.y + dist * wd.y));
          const unsigned short h2 = f2bf(fast_silu(acc1[jt][2] + bx.z + dist * wd.z));
          const unsigned short h3 = f2bf(fast_silu(acc1[jt][3] + bx.w + dist * wd.w));
          const int j0 = jt * 16 + q * 4;
          const int kt2 = j0 >> 5;
          const int lane2 = (((j0 & 31) >> 3) << 4) | nn;
          const int byteoff = (j0 & 7) << 1;
          uint2* dst = (uint2*)((char*)sFeat +
                                (((size_t)((etG * 4 + kt2) * 64 + lane2)) << 4) + byteoff);
          *dst = make_uint2((unsigned int)h0 | ((unsigned int)h1 << 16),
                            (unsigned int)h2 | ((unsigned int)h3 << 16));
        }
      }

      // ---- GEMM2 + epilogue 2 (acc2[4] = 16 regs peak)
      {
        floatx4 acc2[4];
#pragma unroll
        for (int it = 0; it < 4; ++it) acc2[it] = fzero;
#pragma unroll 1
        for (int kt = 0; kt < 4; ++kt) {
          const short8 b = __builtin_bit_cast(short8, sFeat[(etG * 4 + kt) * 64 + lane]);
#pragma unroll
          for (int it = 0; it < 4; ++it) {
            const short8 a = __builtin_bit_cast(short8, wx2f[(kt * 4 + it) * 64 + lane]);
            acc2[it] = MFMA(a, b, acc2[it]);
          }
        }
        const int el = etG * 16 + nn;
        const bool v = (t0 + el) < e1;
        const int lc = sLC[el];
        float* arow = sAccX + lc * 68;
#pragma unroll
        for (int it = 0; it < 4; ++it) {
          const float4 b2 = *(const float4*)(misc + 128 + it * 16 + q * 4);
          if (v) {
            const int i0 = it * 16 + q * 4;
            atomicAdd(arow + i0 + 0, acc2[it][0] + b2.x);
            atomicAdd(arow + i0 + 1, acc2[it][1] + b2.y);
            atomicAdd(arow + i0 + 2, acc2[it][2] + b2.z);
            atomicAdd(arow + i0 + 3, acc2[it][3] + b2.w);
          }
        }
      }
    }
    __syncthreads();
  }

  // ---- final coalesced stores (no global atomics)
  {
    const int n = base + (tid >> 2);
    if (n < NODES) {
      const int c0 = (tid & 3) * 16;
      float* orow = out + (size_t)n * 64 + c0;
      const float* arow = sAccX + (tid >> 2) * 68 + c0;
#pragma unroll
      for (int j = 0; j < 16; j += 4) *(float4*)(orow + j) = *(const float4*)(arow + j);
    }
    if (tid < 192) {
      const int idx = base * 3 + tid;
      if (idx < NODES * 3)
        out[(size_t)NODES * 64 + idx] = sAccP[(tid / 3) * 4 + (tid % 3)];
    }
  }
}

extern "C" void kernel_launch(void* const* d_in, const int* in_sizes, int n_in,
                              void* d_out, int out_size, void* d_ws, size_t ws_size,
                              hipStream_t stream) {
  (void)in_sizes; (void)n_in; (void)ws_size; (void)out_size;
  const float* x = (const float*)d_in[0];
  const float* pos = (const float*)d_in[1];
  const int* ei = (const int*)d_in[2];
  const float* Wx1 = (const float*)d_in[3];
  const float* bx1 = (const float*)d_in[4];
  const float* Wx2 = (const float*)d_in[5];
  const float* bx2 = (const float*)d_in[6];
  const float* Wp1 = (const float*)d_in[7];
  const float* bp1 = (const float*)d_in[8];
  const float* Wp2 = (const float*)d_in[9];
  const float* bp2 = (const float*)d_in[10];
  float* out = (float*)d_out;
  unsigned char* ws = (unsigned char*)d_ws;

  int* counts = (int*)(ws + WS_CNT);   // aliased with cursor (scan3 rewrites)
  int* cursor = (int*)(ws + WS_CNT);
  int* off = (int*)(ws + WS_OFF);
  int* tmp = (int*)(ws + WS_TMP);      // aliased with srec (dies before scatter)
  int* bsum = (int*)(ws + WS_BSUM);
  int* bsumx = (int*)(ws + WS_BSUMX);
  unsigned int* srec = (unsigned int*)(ws + WS_SREC);

  hipMemsetAsync(counts, 0, (size_t)NODES * sizeof(int), stream);
  prep_kernel<<<16, 256, 0, stream>>>(Wx1, Wx2, Wp1, bx1, bx2, bp1, Wp2, bp2, ws);
  const int eb = (EDGES + 255) / 256;
  hist_kernel<<<eb, 256, 0, stream>>>(ei, counts);
  scan1_kernel<<<SCB, 1024, 0, stream>>>(counts, tmp, bsum);
  scan2_kernel<<<1, 128, 0, stream>>>(bsum, bsumx);
  scan3_kernel<<<SCB, 1024, 0, stream>>>(counts, tmp, bsumx, off, cursor);
  scatter_kernel<<<eb, 256, 0, stream>>>(ei, cursor, srec);
  node_kernel<<<NBLK, 256, 0, stream>>>(x, pos, ws, out);
}